// Round 11
// baseline (890.418 us; speedup 1.0000x reference)
//
#include <hip/hip_runtime.h>

using half8 = __attribute__((ext_vector_type(8))) _Float16;
using f32x4 = __attribute__((ext_vector_type(4))) float;

__device__ __forceinline__ float sigmf(float x) {
    return __builtin_amdgcn_rcpf(1.0f + __expf(-x));
}
__device__ __forceinline__ float tanhx(float x) {
    return 1.0f - 2.0f * __builtin_amdgcn_rcpf(1.0f + __expf(x + x));
}

// ---------------------------------------------------------------------------
// Prep (one-time):
//  x16   : [75][112][76] fp16 (transposed x, zero-padded)
//  wihI{0,2}: GEMM-interleaved [4H][Kv] fp16 (row n = gate row (n&3)*H+(n>>2))
//  wihP{1,3,4,5}: plain [4H][HIN] fp16 (in-register B-roles)
//  whhP  : all layers plain [4H][H] fp16
//  biasI : summed bias, interleaved: L0@0 (512), L2@512 (256)
//  biasP : summed bias, plain: L3@0, L4@256, L5@384, L1@512
// ---------------------------------------------------------------------------
struct PrepPtrs {
    const float* wih[6];
    const float* whh[6];
    const float* bi[6];
    const float* bh[6];
    const float* x;
    _Float16* wihI0;
    _Float16* wihP1;
    _Float16* wihI2;
    _Float16* wihP3;
    _Float16* wihP4;
    _Float16* wihP5;
    _Float16* whhP[6];
    float* biasI;
    float* biasP;
    _Float16* x16;
};

__global__ __launch_bounds__(256) void prep_kernel(PrepPtrs p) {
    int i = blockIdx.x * 256 + threadIdx.x;
    if (i < 642048) {  // x16: 8448 rows x 76
        int row = i / 76, k = i - row * 76;
        int t = row / 112, b = row - t * 112;
        float v = (b < 100 && k < 75 && t < 75)
                      ? p.x[((size_t)b * 75 + t) * 75 + k]
                      : 0.0f;
        p.x16[i] = (_Float16)v;
        return;
    }
    i -= 642048;
    if (i < 38912) {  // wihI0 [512][76], K=75, interleaved
        int n = i / 76, k = i - n * 76;
        int col = n >> 2, G = n & 3;
        float v = (k < 75) ? p.wih[0][(size_t)(G * 128 + col) * 75 + k] : 0.0f;
        p.wihI0[i] = (_Float16)v;
        return;
    }
    i -= 38912;
    if (i < 65536) { p.wihP1[i] = (_Float16)p.wih[1][i]; return; }  // plain [512][128]
    i -= 65536;
    if (i < 32768) {  // wihI2 [256][128] interleaved
        int n = i >> 7, k = i & 127;
        int col = n >> 2, G = n & 3;
        p.wihI2[i] = (_Float16)p.wih[2][(size_t)(G * 64 + col) * 128 + k];
        return;
    }
    i -= 32768;
    if (i < 16384) { p.wihP3[i] = (_Float16)p.wih[3][i]; return; }
    i -= 16384;
    if (i < 8192) { p.wihP4[i] = (_Float16)p.wih[4][i]; return; }
    i -= 8192;
    if (i < 4096) { p.wihP5[i] = (_Float16)p.wih[5][i]; return; }
    i -= 4096;
    constexpr int WHHC[6] = {65536, 65536, 16384, 16384, 4096, 4096};
    #pragma unroll
    for (int l = 0; l < 6; ++l) {
        if (i < WHHC[l]) { p.whhP[l][i] = (_Float16)p.whh[l][i]; return; }
        i -= WHHC[l];
    }
    if (i < 512) {  // biasI L0 (H=128) interleaved
        int col = i >> 2, G = i & 3;
        int src = G * 128 + col;
        p.biasI[i] = p.bi[0][src] + p.bh[0][src];
        return;
    }
    i -= 512;
    if (i < 256) {  // biasI L2 (H=64) interleaved @512
        int col = i >> 2, G = i & 3;
        int src = G * 64 + col;
        p.biasI[512 + i] = p.bi[2][src] + p.bh[2][src];
        return;
    }
    i -= 256;
    if (i < 256) { p.biasP[i] = p.bi[3][i] + p.bh[3][i]; return; }
    i -= 256;
    if (i < 128) { p.biasP[256 + i] = p.bi[4][i] + p.bh[4][i]; return; }
    i -= 128;
    if (i < 128) { p.biasP[384 + i] = p.bi[5][i] + p.bh[5][i]; return; }
    i -= 128;
    if (i < 512) { p.biasP[512 + i] = p.bi[1][i] + p.bh[1][i]; return; }
}

// ---------------------------------------------------------------------------
// xg GEMM (round-7 proven): layout [75][28][4H][4] f32; a lane's f32x4 at
// (n, bs0..3) is one MFMA C fragment (rows = batch).
// ---------------------------------------------------------------------------
template <int Ks>
__global__ __launch_bounds__(256) void gemm_xg(
    const _Float16* __restrict__ A, const _Float16* __restrict__ W,
    const float* __restrict__ bias, float* __restrict__ C, int Kv, int N) {
    constexpr int KP = Ks * 32;
    constexpr int LDK = KP + 8;
    __shared__ __align__(16) _Float16 Al[64][LDK];
    __shared__ __align__(16) _Float16 Wl[64][LDK];

    const int tid = threadIdx.x;
    const int tt = blockIdx.x >> 1;
    const int boff = (blockIdx.x & 1) * 48;
    const int n0 = blockIdx.y * 64;
    constexpr int HP = KP / 2;

    for (int idx = tid; idx < 64 * HP; idx += 256) {
        int row = idx / HP;
        int k = (idx - row * HP) * 2;
        unsigned int va = 0, vw = 0;
        if (k < Kv) {
            va = *(const unsigned int*)(A + (size_t)(tt * 112 + boff + row) * Kv + k);
            vw = *(const unsigned int*)(W + (size_t)(n0 + row) * Kv + k);
        }
        *(unsigned int*)&Al[row][k] = va;
        *(unsigned int*)&Wl[row][k] = vw;
    }
    __syncthreads();

    const int w = tid >> 6, l = tid & 63, hi = l >> 4;
    half8 a[Ks];
    #pragma unroll
    for (int kk = 0; kk < Ks; ++kk)
        a[kk] = *(const half8*)&Al[w * 16 + (l & 15)][kk * 32 + hi * 8];

    f32x4 acc[4];
    #pragma unroll
    for (int jt = 0; jt < 4; ++jt) {
        acc[jt] = f32x4{0.f, 0.f, 0.f, 0.f};
        #pragma unroll
        for (int kk = 0; kk < Ks; ++kk) {
            half8 b = *(const half8*)&Wl[jt * 16 + (l & 15)][kk * 32 + hi * 8];
            acc[jt] = __builtin_amdgcn_mfma_f32_16x16x32_f16(a[kk], b, acc[jt], 0, 0, 0);
        }
    }

    const int bx = (boff >> 2) + w * 4 + hi;
    #pragma unroll
    for (int jt = 0; jt < 4; ++jt) {
        int n = n0 + jt * 16 + (l & 15);
        float bs = bias[n];
        f32x4 v = acc[jt];
        v[0] += bs; v[1] += bs; v[2] += bs; v[3] += bs;
        *(f32x4*)(C + ((size_t)(tt * 28 + bx) * N + n) * 4) = v;
    }
}

#define FTAIL                                                                 \
    __builtin_amdgcn_sched_barrier(0);                                        \
    asm volatile("s_waitcnt lgkmcnt(0)");                                     \
    __builtin_amdgcn_sched_barrier(0);                                        \
    __builtin_amdgcn_s_barrier();                                             \
    __builtin_amdgcn_sched_barrier(0);

#define PICK(A4) ((hi & 2) ? ((hi & 1) ? A4[3] : A4[2]) : ((hi & 1) ? A4[1] : A4[0]))

#define ACT(aI, aF, aG4, aO)                                                  \
    float gI = PICK(aI), gF = PICK(aF), gG = PICK(aG4), gO = PICK(aO);        \
    float si = sigmf(gI), sf = sigmf(gF), tg = tanhx(gG), so = sigmf(gO);     \
    float cn = sf * cst + si * tg;                                            \
    cst = cn;                                                                 \
    float hn = so * tanhx(cn);                                                \
    _Float16 hv = (_Float16)hn;

// ---------------------------------------------------------------------------
// Fused layer PAIR (round-9 proven), here used at H=128 for layers 0+1:
// waves [0,NW) = layer A (xg C-init, 3-deep P prefetch); waves [NW,2NW) =
// layer B one step behind, consuming h^A from the LDS pipe hp, with whhB and
// wihB both in registers. One barrier per step, 76 steps. Only B's h goes
// to global.
// ---------------------------------------------------------------------------
template <int H>
__global__ __launch_bounds__(8 * H) void lstm_pair(
    const float* __restrict__ xg,        // [75+3][28][4H][4] f32 (layer A)
    const _Float16* __restrict__ whhA,   // [4H][H]
    const _Float16* __restrict__ whhB,   // [4H][H]
    const _Float16* __restrict__ wihB,   // [4H][H]
    const float* __restrict__ biasB,     // [4H] plain
    _Float16* __restrict__ houtB) {      // [75][112][H]
    constexpr int Ks = H / 32;
    constexpr int NW = H / 16;
    constexpr int LDH = H + 8;
    constexpr int XSTR = 448 * H;
    constexpr int HSTR = 112 * H;

    __shared__ __align__(16) _Float16 hbA[2][4][LDH];
    __shared__ __align__(16) _Float16 hbB[2][4][LDH];
    __shared__ __align__(16) _Float16 hp[2][4][LDH];

    const int tid = threadIdx.x;
    const int w = tid >> 6, l = tid & 63, hi = l >> 4;
    const bool isA = (w < NW);
    const int wl = isA ? w : (w - NW);
    const int col = wl * 16 + (l & 15);
    const int blk = blockIdx.x;

    half8 bwA[4][Ks], bwB[4][Ks], bwI[4][Ks];
    float bI = 0.f, bF = 0.f, bG = 0.f, bO = 0.f;
    if (isA) {
        #pragma unroll
        for (int G = 0; G < 4; ++G)
            #pragma unroll
            for (int kk = 0; kk < Ks; ++kk)
                bwA[G][kk] = *(const half8*)(whhA + (size_t)(G * H + col) * H + kk * 32 + hi * 8);
    } else {
        #pragma unroll
        for (int G = 0; G < 4; ++G)
            #pragma unroll
            for (int kk = 0; kk < Ks; ++kk) {
                bwB[G][kk] = *(const half8*)(whhB + (size_t)(G * H + col) * H + kk * 32 + hi * 8);
                bwI[G][kk] = *(const half8*)(wihB + (size_t)(G * H + col) * H + kk * 32 + hi * 8);
            }
        bI = biasB[0 * H + col];
        bF = biasB[1 * H + col];
        bG = biasB[2 * H + col];
        bO = biasB[3 * H + col];
    }

    for (int i = tid; i < 2 * 4 * LDH; i += 8 * H) {
        ((_Float16*)hbA)[i] = (_Float16)0;
        ((_Float16*)hbB)[i] = (_Float16)0;
        ((_Float16*)hp)[i] = (_Float16)0;
    }
    __syncthreads();

    const float* xp = xg + (size_t)blk * (4 * H * 4) + col * 16;
    _Float16* hop = houtB + (size_t)(blk * 4 + hi) * H + col;

    f32x4 P0[4], P1[4], P2[4];
#define XLOADP(PA)                                                            \
    PA[0] = *(const f32x4*)(xp + 0);                                          \
    PA[1] = *(const f32x4*)(xp + 4);                                          \
    PA[2] = *(const f32x4*)(xp + 8);                                          \
    PA[3] = *(const f32x4*)(xp + 12);                                         \
    xp += XSTR;

    if (isA) {
        XLOADP(P0)
        XLOADP(P1)
        XLOADP(P2)
    }

    float cst = 0.f;

#define ASTEP(PA, CUR)                                                        \
    {                                                                         \
        half8 afr[Ks];                                                        \
        _Pragma("unroll") for (int kk = 0; kk < Ks; ++kk)                     \
            afr[kk] = *(const half8*)&hbA[CUR][(l & 15) & 3][kk * 32 + hi * 8]; \
        f32x4 aI = PA[0], aF = PA[1], aG4 = PA[2], aO = PA[3];                \
        XLOADP(PA)                                                            \
        _Pragma("unroll") for (int kk = 0; kk < Ks; ++kk) {                   \
            aI = __builtin_amdgcn_mfma_f32_16x16x32_f16(afr[kk], bwA[0][kk], aI, 0, 0, 0); \
            aF = __builtin_amdgcn_mfma_f32_16x16x32_f16(afr[kk], bwA[1][kk], aF, 0, 0, 0); \
            aG4 = __builtin_amdgcn_mfma_f32_16x16x32_f16(afr[kk], bwA[2][kk], aG4, 0, 0, 0); \
            aO = __builtin_amdgcn_mfma_f32_16x16x32_f16(afr[kk], bwA[3][kk], aO, 0, 0, 0); \
        }                                                                     \
        ACT(aI, aF, aG4, aO)                                                  \
        hbA[CUR ^ 1][hi][col] = hv;                                           \
        hp[CUR ^ 1][hi][col] = hv;                                            \
    }

#define BSTEP(CUR)                                                            \
    {                                                                         \
        half8 afr[Ks], air[Ks];                                               \
        _Pragma("unroll") for (int kk = 0; kk < Ks; ++kk) {                   \
            afr[kk] = *(const half8*)&hbB[CUR][(l & 15) & 3][kk * 32 + hi * 8]; \
            air[kk] = *(const half8*)&hp[CUR][(l & 15) & 3][kk * 32 + hi * 8]; \
        }                                                                     \
        f32x4 aI = {bI, bI, bI, bI}, aF = {bF, bF, bF, bF};                   \
        f32x4 aG4 = {bG, bG, bG, bG}, aO = {bO, bO, bO, bO};                  \
        _Pragma("unroll") for (int kk = 0; kk < Ks; ++kk) {                   \
            aI = __builtin_amdgcn_mfma_f32_16x16x32_f16(afr[kk], bwB[0][kk], aI, 0, 0, 0); \
            aF = __builtin_amdgcn_mfma_f32_16x16x32_f16(afr[kk], bwB[1][kk], aF, 0, 0, 0); \
            aG4 = __builtin_amdgcn_mfma_f32_16x16x32_f16(afr[kk], bwB[2][kk], aG4, 0, 0, 0); \
            aO = __builtin_amdgcn_mfma_f32_16x16x32_f16(afr[kk], bwB[3][kk], aO, 0, 0, 0); \
        }                                                                     \
        _Pragma("unroll") for (int kk = 0; kk < Ks; ++kk) {                   \
            aI = __builtin_amdgcn_mfma_f32_16x16x32_f16(air[kk], bwI[0][kk], aI, 0, 0, 0); \
            aF = __builtin_amdgcn_mfma_f32_16x16x32_f16(air[kk], bwI[1][kk], aF, 0, 0, 0); \
            aG4 = __builtin_amdgcn_mfma_f32_16x16x32_f16(air[kk], bwI[2][kk], aG4, 0, 0, 0); \
            aO = __builtin_amdgcn_mfma_f32_16x16x32_f16(air[kk], bwI[3][kk], aO, 0, 0, 0); \
        }                                                                     \
        ACT(aI, aF, aG4, aO)                                                  \
        hbB[CUR ^ 1][hi][col] = hv;                                           \
        *hop = hv;                                                            \
        hop += HSTR;                                                          \
    }

#define PSTEP(PA, CUR, S)                                                     \
    {                                                                         \
        if (isA) {                                                            \
            ASTEP(PA, CUR)                                                    \
        } else if ((S) > 0) {                                                 \
            BSTEP(CUR)                                                        \
        }                                                                     \
        FTAIL                                                                 \
    }

    #pragma unroll 1
    for (int it = 0; it < 12; ++it) {
        const int b6 = it * 6;
        PSTEP(P0, 0, b6 + 0) PSTEP(P1, 1, b6 + 1) PSTEP(P2, 0, b6 + 2)
        PSTEP(P0, 1, b6 + 3) PSTEP(P1, 0, b6 + 4) PSTEP(P2, 1, b6 + 5)
    }
    PSTEP(P0, 0, 72) PSTEP(P1, 1, 73) PSTEP(P2, 0, 74)
    {  // s = 75: B finishes t = 74
        if (!isA) { BSTEP(1) }
        FTAIL
    }
#undef PSTEP
#undef BSTEP
#undef ASTEP
#undef XLOADP
}

// ---------------------------------------------------------------------------
// Quad-fused layers 2,3,4,5 (round-10 proven, unchanged). 25 blocks x 768
// threads: w0-3 = L2 (xg C-init), w4-7 = L3 (lag 1), w8-9 = L4 (lag 2),
// w10-11 = L5 (lag 3, writes h5). 78 steps, one barrier each.
// ---------------------------------------------------------------------------
__global__ __launch_bounds__(768) void lstm_quad(
    const float* __restrict__ xg,        // [78][28][256][4] f32 (layer 2)
    const _Float16* __restrict__ whh2, const _Float16* __restrict__ whh3,
    const _Float16* __restrict__ wih3, const _Float16* __restrict__ whh4,
    const _Float16* __restrict__ wih4, const _Float16* __restrict__ whh5,
    const _Float16* __restrict__ wih5, const float* __restrict__ biasP,
    _Float16* __restrict__ hout) {       // [75][112][32]
    __shared__ __align__(16) _Float16 hb2[2][4][72], hp2[2][4][72];
    __shared__ __align__(16) _Float16 hb3[2][4][72], hp3[2][4][72];
    __shared__ __align__(16) _Float16 hb4[2][4][40], hp4[2][4][40];
    __shared__ __align__(16) _Float16 hb5[2][4][40];

    const int tid = threadIdx.x;
    const int w = tid >> 6, l = tid & 63, hi = l >> 4;
    const int lr = (l & 15) & 3;
    const int blk = blockIdx.x;

    for (int i = tid; i < 2 * 4 * 72; i += 768) {
        ((_Float16*)hb2)[i] = (_Float16)0; ((_Float16*)hp2)[i] = (_Float16)0;
        ((_Float16*)hb3)[i] = (_Float16)0; ((_Float16*)hp3)[i] = (_Float16)0;
    }
    for (int i = tid; i < 2 * 4 * 40; i += 768) {
        ((_Float16*)hb4)[i] = (_Float16)0; ((_Float16*)hp4)[i] = (_Float16)0;
        ((_Float16*)hb5)[i] = (_Float16)0;
    }
    __syncthreads();

    float cst = 0.f;

    if (w < 4) {  // ----- L2: xg C-init role -----
        const int col = w * 16 + (l & 15);
        half8 bw[4][2];
        #pragma unroll
        for (int G = 0; G < 4; ++G)
            #pragma unroll
            for (int kk = 0; kk < 2; ++kk)
                bw[G][kk] = *(const half8*)(whh2 + (size_t)(G * 64 + col) * 64 + kk * 32 + hi * 8);
        const float* xp = xg + (size_t)blk * 1024 + col * 16;
        f32x4 P0[4], P1[4], P2[4];
#define XLOADQ(PA)                                                            \
        PA[0] = *(const f32x4*)(xp + 0);                                      \
        PA[1] = *(const f32x4*)(xp + 4);                                      \
        PA[2] = *(const f32x4*)(xp + 8);                                      \
        PA[3] = *(const f32x4*)(xp + 12);                                     \
        xp += 28672;
        XLOADQ(P0)
        XLOADQ(P1)
        XLOADQ(P2)

#define QA(PA, CUR, S)                                                        \
        {                                                                     \
            if ((S) < 75) {                                                   \
                half8 afr[2];                                                 \
                _Pragma("unroll") for (int kk = 0; kk < 2; ++kk)              \
                    afr[kk] = *(const half8*)&hb2[CUR][lr][kk * 32 + hi * 8]; \
                f32x4 aI = PA[0], aF = PA[1], aG4 = PA[2], aO = PA[3];        \
                XLOADQ(PA)                                                    \
                _Pragma("unroll") for (int kk = 0; kk < 2; ++kk) {            \
                    aI = __builtin_amdgcn_mfma_f32_16x16x32_f16(afr[kk], bw[0][kk], aI, 0, 0, 0);  \
                    aF = __builtin_amdgcn_mfma_f32_16x16x32_f16(afr[kk], bw[1][kk], aF, 0, 0, 0);  \
                    aG4 = __builtin_amdgcn_mfma_f32_16x16x32_f16(afr[kk], bw[2][kk], aG4, 0, 0, 0);\
                    aO = __builtin_amdgcn_mfma_f32_16x16x32_f16(afr[kk], bw[3][kk], aO, 0, 0, 0);  \
                }                                                             \
                ACT(aI, aF, aG4, aO)                                          \
                hb2[(CUR) ^ 1][hi][col] = hv;                                 \
                hp2[(CUR) ^ 1][hi][col] = hv;                                 \
            }                                                                 \
            FTAIL                                                             \
        }
        #pragma unroll 1
        for (int it = 0; it < 13; ++it) {
            const int b6 = it * 6;
            QA(P0, 0, b6 + 0) QA(P1, 1, b6 + 1) QA(P2, 0, b6 + 2)
            QA(P0, 1, b6 + 3) QA(P1, 0, b6 + 4) QA(P2, 1, b6 + 5)
        }
#undef QA
#undef XLOADQ
    } else if (w < 8) {  // ----- L3: H=64, HIN=64, lag 1 -----
        const int col = (w - 4) * 16 + (l & 15);
        half8 bwB[4][2], bwI[4][2];
        #pragma unroll
        for (int G = 0; G < 4; ++G)
            #pragma unroll
            for (int kk = 0; kk < 2; ++kk) {
                bwB[G][kk] = *(const half8*)(whh3 + (size_t)(G * 64 + col) * 64 + kk * 32 + hi * 8);
                bwI[G][kk] = *(const half8*)(wih3 + (size_t)(G * 64 + col) * 64 + kk * 32 + hi * 8);
            }
        const float bI = biasP[col], bF = biasP[64 + col];
        const float bG = biasP[128 + col], bO = biasP[192 + col];
        #pragma unroll 1
        for (int s = 0; s < 78; ++s) {
            const int cur = s & 1;
            if (s >= 1 && s <= 75) {
                half8 afr[2], air[2];
                #pragma unroll
                for (int kk = 0; kk < 2; ++kk) {
                    afr[kk] = *(const half8*)&hb3[cur][lr][kk * 32 + hi * 8];
                    air[kk] = *(const half8*)&hp2[cur][lr][kk * 32 + hi * 8];
                }
                f32x4 aI = {bI, bI, bI, bI}, aF = {bF, bF, bF, bF};
                f32x4 aG4 = {bG, bG, bG, bG}, aO = {bO, bO, bO, bO};
                #pragma unroll
                for (int kk = 0; kk < 2; ++kk) {
                    aI = __builtin_amdgcn_mfma_f32_16x16x32_f16(afr[kk], bwB[0][kk], aI, 0, 0, 0);
                    aF = __builtin_amdgcn_mfma_f32_16x16x32_f16(afr[kk], bwB[1][kk], aF, 0, 0, 0);
                    aG4 = __builtin_amdgcn_mfma_f32_16x16x32_f16(afr[kk], bwB[2][kk], aG4, 0, 0, 0);
                    aO = __builtin_amdgcn_mfma_f32_16x16x32_f16(afr[kk], bwB[3][kk], aO, 0, 0, 0);
                }
                #pragma unroll
                for (int kk = 0; kk < 2; ++kk) {
                    aI = __builtin_amdgcn_mfma_f32_16x16x32_f16(air[kk], bwI[0][kk], aI, 0, 0, 0);
                    aF = __builtin_amdgcn_mfma_f32_16x16x32_f16(air[kk], bwI[1][kk], aF, 0, 0, 0);
                    aG4 = __builtin_amdgcn_mfma_f32_16x16x32_f16(air[kk], bwI[2][kk], aG4, 0, 0, 0);
                    aO = __builtin_amdgcn_mfma_f32_16x16x32_f16(air[kk], bwI[3][kk], aO, 0, 0, 0);
                }
                ACT(aI, aF, aG4, aO)
                hb3[cur ^ 1][hi][col] = hv;
                hp3[cur ^ 1][hi][col] = hv;
            }
            FTAIL
        }
    } else if (w < 10) {  // ----- L4: H=32, HIN=64, lag 2 -----
        const int col = (w - 8) * 16 + (l & 15);
        half8 bwB[4], bwI[4][2];
        #pragma unroll
        for (int G = 0; G < 4; ++G) {
            bwB[G] = *(const half8*)(whh4 + (size_t)(G * 32 + col) * 32 + hi * 8);
            #pragma unroll
            for (int kk = 0; kk < 2; ++kk)
                bwI[G][kk] = *(const half8*)(wih4 + (size_t)(G * 32 + col) * 64 + kk * 32 + hi * 8);
        }
        const float* bp = biasP + 256;
        const float bI = bp[col], bF = bp[32 + col], bG = bp[64 + col], bO = bp[96 + col];
        #pragma unroll 1
        for (int s = 0; s < 78; ++s) {
            const int cur = s & 1;
            if (s >= 2 && s <= 76) {
                half8 afr = *(const half8*)&hb4[cur][lr][hi * 8];
                half8 air[2];
                #pragma unroll
                for (int kk = 0; kk < 2; ++kk)
                    air[kk] = *(const half8*)&hp3[cur][lr][kk * 32 + hi * 8];
                f32x4 aI = {bI, bI, bI, bI}, aF = {bF, bF, bF, bF};
                f32x4 aG4 = {bG, bG, bG, bG}, aO = {bO, bO, bO, bO};
                aI = __builtin_amdgcn_mfma_f32_16x16x32_f16(afr, bwB[0], aI, 0, 0, 0);
                aF = __builtin_amdgcn_mfma_f32_16x16x32_f16(afr, bwB[1], aF, 0, 0, 0);
                aG4 = __builtin_amdgcn_mfma_f32_16x16x32_f16(afr, bwB[2], aG4, 0, 0, 0);
                aO = __builtin_amdgcn_mfma_f32_16x16x32_f16(afr, bwB[3], aO, 0, 0, 0);
                #pragma unroll
                for (int kk = 0; kk < 2; ++kk) {
                    aI = __builtin_amdgcn_mfma_f32_16x16x32_f16(air[kk], bwI[0][kk], aI, 0, 0, 0);
                    aF = __builtin_amdgcn_mfma_f32_16x16x32_f16(air[kk], bwI[1][kk], aF, 0, 0, 0);
                    aG4 = __builtin_amdgcn_mfma_f32_16x16x32_f16(air[kk], bwI[2][kk], aG4, 0, 0, 0);
                    aO = __builtin_amdgcn_mfma_f32_16x16x32_f16(air[kk], bwI[3][kk], aO, 0, 0, 0);
                }
                ACT(aI, aF, aG4, aO)
                hb4[cur ^ 1][hi][col] = hv;
                hp4[cur ^ 1][hi][col] = hv;
            }
            FTAIL
        }
    } else {  // ----- L5: H=32, HIN=32, lag 3; writes h5 -----
        const int col = (w - 10) * 16 + (l & 15);
        half8 bwB[4], bwI[4];
        #pragma unroll
        for (int G = 0; G < 4; ++G) {
            bwB[G] = *(const half8*)(whh5 + (size_t)(G * 32 + col) * 32 + hi * 8);
            bwI[G] = *(const half8*)(wih5 + (size_t)(G * 32 + col) * 32 + hi * 8);
        }
        const float* bp = biasP + 384;
        const float bI = bp[col], bF = bp[32 + col], bG = bp[64 + col], bO = bp[96 + col];
        _Float16* hop = hout + (size_t)(blk * 4 + hi) * 32 + col;
        #pragma unroll 1
        for (int s = 0; s < 78; ++s) {
            const int cur = s & 1;
            if (s >= 3) {
                half8 afr = *(const half8*)&hb5[cur][lr][hi * 8];
                half8 air = *(const half8*)&hp4[cur][lr][hi * 8];
                f32x4 aI = {bI, bI, bI, bI}, aF = {bF, bF, bF, bF};
                f32x4 aG4 = {bG, bG, bG, bG}, aO = {bO, bO, bO, bO};
                aI = __builtin_amdgcn_mfma_f32_16x16x32_f16(afr, bwB[0], aI, 0, 0, 0);
                aF = __builtin_amdgcn_mfma_f32_16x16x32_f16(afr, bwB[1], aF, 0, 0, 0);
                aG4 = __builtin_amdgcn_mfma_f32_16x16x32_f16(afr, bwB[2], aG4, 0, 0, 0);
                aO = __builtin_amdgcn_mfma_f32_16x16x32_f16(afr, bwB[3], aO, 0, 0, 0);
                aI = __builtin_amdgcn_mfma_f32_16x16x32_f16(air, bwI[0], aI, 0, 0, 0);
                aF = __builtin_amdgcn_mfma_f32_16x16x32_f16(air, bwI[1], aF, 0, 0, 0);
                aG4 = __builtin_amdgcn_mfma_f32_16x16x32_f16(air, bwI[2], aG4, 0, 0, 0);
                aO = __builtin_amdgcn_mfma_f32_16x16x32_f16(air, bwI[3], aO, 0, 0, 0);
                ACT(aI, aF, aG4, aO)
                hb5[cur ^ 1][hi][col] = hv;
                *hop = hv;
                hop += 3584;
            }
            FTAIL
        }
    }
}

// ---------------------------------------------------------------------------
// Final linear: out[100][60] = h5 @ lin_w^T + lin_b; h5 is [75][112][32] fp16.
// ---------------------------------------------------------------------------
__global__ __launch_bounds__(256) void linear_out(
    const _Float16* __restrict__ h, const float* __restrict__ lw,
    const float* __restrict__ lb, float* __restrict__ out) {
    int wave = (blockIdx.x * 256 + threadIdx.x) >> 6;
    int l = threadIdx.x & 63;
    if (wave >= 6000) return;
    int b = wave / 60, o = wave - b * 60;
    int hc = l & 31, t0 = l >> 5;
    float acc = 0.f;
    for (int t = t0; t < 75; t += 2)
        acc += (float)h[((size_t)t * 112 + b) * 32 + hc] * lw[(size_t)o * 2400 + t * 32 + hc];
    #pragma unroll
    for (int s = 32; s; s >>= 1) acc += __shfl_xor(acc, s, 64);
    if (l == 0) out[b * 60 + o] = acc + lb[o];
}

// ---------------------------------------------------------------------------
extern "C" void kernel_launch(void* const* d_in, const int* in_sizes, int n_in,
                              void* d_out, int out_size, void* d_ws, size_t ws_size,
                              hipStream_t stream) {
    const float* x = (const float*)d_in[0];
    const float* wih[6];
    const float* whhp[6];
    const float* bih[6];
    const float* bhh[6];
    for (int i = 0; i < 6; ++i) {
        wih[i] = (const float*)d_in[1 + 4 * i];
        whhp[i] = (const float*)d_in[2 + 4 * i];
        bih[i] = (const float*)d_in[3 + 4 * i];
        bhh[i] = (const float*)d_in[4 + 4 * i];
    }
    const float* lw = (const float*)d_in[25];
    const float* lb = (const float*)d_in[26];
    float* out = (float*)d_out;

    char* ws = (char*)d_ws;
    size_t cur = 0;
    auto alloc = [&](size_t b) {
        size_t o = cur;
        cur += (b + 255) & ~(size_t)255;
        return o;
    };
    _Float16* x16 = (_Float16*)(ws + alloc((size_t)8448 * 76 * 2));
    _Float16* wihI0 = (_Float16*)(ws + alloc(38912 * 2));
    _Float16* wihP1 = (_Float16*)(ws + alloc(65536 * 2));
    _Float16* wihI2 = (_Float16*)(ws + alloc(32768 * 2));
    _Float16* wihP3 = (_Float16*)(ws + alloc(16384 * 2));
    _Float16* wihP4 = (_Float16*)(ws + alloc(8192 * 2));
    _Float16* wihP5 = (_Float16*)(ws + alloc(4096 * 2));
    _Float16* whhP[6];
    const size_t whhBytes[6] = {131072, 131072, 32768, 32768, 8192, 8192};
    for (int i = 0; i < 6; ++i) whhP[i] = (_Float16*)(ws + alloc(whhBytes[i]));
    float* biasI = (float*)(ws + alloc(768 * 4));
    float* biasP = (float*)(ws + alloc(1024 * 4));
    float* xg = (float*)(ws + alloc((size_t)78 * 28 * 512 * 4 * 4));
    _Float16* h1 = (_Float16*)(ws + alloc((size_t)75 * 112 * 128 * 2));
    _Float16* h5 = (_Float16*)(ws + alloc((size_t)75 * 112 * 32 * 2));

    PrepPtrs pp;
    for (int i = 0; i < 6; ++i) {
        pp.wih[i] = wih[i];
        pp.whh[i] = whhp[i];
        pp.bi[i] = bih[i];
        pp.bh[i] = bhh[i];
        pp.whhP[i] = whhP[i];
    }
    pp.x = x;
    pp.wihI0 = wihI0;
    pp.wihP1 = wihP1;
    pp.wihI2 = wihI2;
    pp.wihP3 = wihP3;
    pp.wihP4 = wihP4;
    pp.wihP5 = wihP5;
    pp.biasI = biasI;
    pp.biasP = biasP;
    pp.x16 = x16;
    prep_kernel<<<3835, 256, 0, stream>>>(pp);

    // layer 0 xg GEMM (I=75, Kv=76, H=128), then pair-fused layers 0+1
    gemm_xg<3><<<dim3(150, 8), 256, 0, stream>>>(x16, wihI0, biasI + 0, xg, 76, 512);
    lstm_pair<128><<<25, 1024, 0, stream>>>(xg, whhP[0], whhP[1], wihP1,
                                            biasP + 512, h1);
    // layer 2 xg GEMM (I=128, H=64), then quad-fused layers 2..5
    gemm_xg<4><<<dim3(150, 4), 256, 0, stream>>>(h1, wihI2, biasI + 512, xg, 128, 256);
    lstm_quad<<<25, 768, 0, stream>>>(xg, whhP[2], whhP[3], wihP3, whhP[4],
                                      wihP4, whhP[5], wihP5, biasP, h5);

    linear_out<<<1500, 256, 0, stream>>>(h5, lw, lb, out);
}

// Round 12
// 180.436 us; speedup vs baseline: 4.9348x; 4.9348x over previous
//
#include <hip/hip_runtime.h>

using half8 = __attribute__((ext_vector_type(8))) _Float16;
using f32x4 = __attribute__((ext_vector_type(4))) float;

__device__ __forceinline__ float sigmf(float x) {
    return __builtin_amdgcn_rcpf(1.0f + __expf(-x));
}
__device__ __forceinline__ float tanhx(float x) {
    return 1.0f - 2.0f * __builtin_amdgcn_rcpf(1.0f + __expf(x + x));
}

// ---------------------------------------------------------------------------
// Prep (one-time):
//  wihI{0,1,2}: GEMM-interleaved [4H][Kv] fp16 (row n = gate row (n&3)*H+(n>>2))
//  wihP{3,4,5}: plain [4H][HIN] fp16 (in-register quad roles)
//  whhP  : all layers plain [4H][H] fp16
//  biasI : summed bias, interleaved, layers 0(@0),1(@512),2(@1024)
//  biasP : summed bias, plain, layers 3(@0),4(@256),5(@384)
//  lwI   : lin_w as [75][4][16][32] fp16: lwI[t][tile][o'][hc] = lw[tile*16+o'][t*32+hc]
// (x is consumed as f32 directly by gemm_xg0 -- no x16 buffer.)
// ---------------------------------------------------------------------------
struct PrepPtrs {
    const float* wih[6];
    const float* whh[6];
    const float* bi[6];
    const float* bh[6];
    const float* lw;
    _Float16* wihI0;
    _Float16* wihI1;
    _Float16* wihI2;
    _Float16* wihP3;
    _Float16* wihP4;
    _Float16* wihP5;
    _Float16* whhP[6];
    float* biasI;
    float* biasP;
    _Float16* lwI;
};

__global__ __launch_bounds__(256) void prep_kernel(PrepPtrs p) {
    int i = blockIdx.x * 256 + threadIdx.x;
    if (i < 38912) {  // wihI0 [512][76], K=75, interleaved
        int n = i / 76, k = i - n * 76;
        int col = n >> 2, G = n & 3;
        float v = (k < 75) ? p.wih[0][(size_t)(G * 128 + col) * 75 + k] : 0.0f;
        p.wihI0[i] = (_Float16)v;
        return;
    }
    i -= 38912;
    if (i < 65536) {  // wihI1 [512][128]
        int n = i >> 7, k = i & 127;
        int col = n >> 2, G = n & 3;
        p.wihI1[i] = (_Float16)p.wih[1][(size_t)(G * 128 + col) * 128 + k];
        return;
    }
    i -= 65536;
    if (i < 32768) {  // wihI2 [256][128]
        int n = i >> 7, k = i & 127;
        int col = n >> 2, G = n & 3;
        p.wihI2[i] = (_Float16)p.wih[2][(size_t)(G * 64 + col) * 128 + k];
        return;
    }
    i -= 32768;
    if (i < 16384) { p.wihP3[i] = (_Float16)p.wih[3][i]; return; }
    i -= 16384;
    if (i < 8192) { p.wihP4[i] = (_Float16)p.wih[4][i]; return; }
    i -= 8192;
    if (i < 4096) { p.wihP5[i] = (_Float16)p.wih[5][i]; return; }
    i -= 4096;
    constexpr int WHHC[6] = {65536, 65536, 16384, 16384, 4096, 4096};
    #pragma unroll
    for (int l = 0; l < 6; ++l) {
        if (i < WHHC[l]) { p.whhP[l][i] = (_Float16)p.whh[l][i]; return; }
        i -= WHHC[l];
    }
    if (i < 153600) {  // lwI [75][4][16][32]
        int t = i >> 11;
        int rem = i & 2047;
        int tile = rem >> 9, op = (rem >> 5) & 15, hc = rem & 31;
        int o = tile * 16 + op;
        float v = (o < 60) ? p.lw[(size_t)o * 2400 + t * 32 + hc] : 0.0f;
        p.lwI[i] = (_Float16)v;
        return;
    }
    i -= 153600;
    // biasI interleaved: L0(H=128)@0, L1(128)@512, L2(64)@1024
    constexpr int BIH[3] = {128, 128, 64};
    constexpr int BIO[3] = {0, 512, 1024};
    #pragma unroll
    for (int j = 0; j < 3; ++j) {
        int cnt = 4 * BIH[j];
        if (i < cnt) {
            int col = i >> 2, G = i & 3;
            int src = G * BIH[j] + col;
            p.biasI[BIO[j] + i] = p.bi[j][src] + p.bh[j][src];
            return;
        }
        i -= cnt;
    }
    if (i < 256) { p.biasP[i] = p.bi[3][i] + p.bh[3][i]; return; }
    i -= 256;
    if (i < 128) { p.biasP[256 + i] = p.bi[4][i] + p.bh[4][i]; return; }
    i -= 128;
    if (i < 128) { p.biasP[384 + i] = p.bi[5][i] + p.bh[5][i]; return; }
}

// ---------------------------------------------------------------------------
// Layer-0 xg GEMM reading f32 x directly (converts during LDS staging).
// Output layout [75][28][512][4] f32 (round-7 proven fragment layout).
// ---------------------------------------------------------------------------
__global__ __launch_bounds__(256) void gemm_xg0(
    const float* __restrict__ X,        // [100][75][75] f32
    const _Float16* __restrict__ W,     // wihI0 [512][76]
    const float* __restrict__ bias, float* __restrict__ C) {
    constexpr int Ks = 3, KP = 96, LDK = 104, HP = 48, Kv = 76, N = 512;
    __shared__ __align__(16) _Float16 Al[64][LDK];
    __shared__ __align__(16) _Float16 Wl[64][LDK];

    const int tid = threadIdx.x;
    const int tt = blockIdx.x >> 1;
    const int boff = (blockIdx.x & 1) * 48;
    const int n0 = blockIdx.y * 64;

    for (int idx = tid; idx < 64 * HP; idx += 256) {
        int row = idx / HP;
        int k = (idx - row * HP) * 2;
        unsigned int va = 0, vw = 0;
        int b = boff + row;
        if (b < 100 && k < 75) {
            float f0 = X[((size_t)b * 75 + tt) * 75 + k];
            float f1 = (k + 1 < 75) ? X[((size_t)b * 75 + tt) * 75 + k + 1] : 0.0f;
            _Float16 h2[2] = {(_Float16)f0, (_Float16)f1};
            va = *(unsigned int*)h2;
        }
        if (k < Kv) vw = *(const unsigned int*)(W + (size_t)(n0 + row) * Kv + k);
        *(unsigned int*)&Al[row][k] = va;
        *(unsigned int*)&Wl[row][k] = vw;
    }
    __syncthreads();

    const int w = tid >> 6, l = tid & 63, hi = l >> 4;
    half8 a[Ks];
    #pragma unroll
    for (int kk = 0; kk < Ks; ++kk)
        a[kk] = *(const half8*)&Al[w * 16 + (l & 15)][kk * 32 + hi * 8];

    f32x4 acc[4];
    #pragma unroll
    for (int jt = 0; jt < 4; ++jt) {
        acc[jt] = f32x4{0.f, 0.f, 0.f, 0.f};
        #pragma unroll
        for (int kk = 0; kk < Ks; ++kk) {
            half8 b = *(const half8*)&Wl[jt * 16 + (l & 15)][kk * 32 + hi * 8];
            acc[jt] = __builtin_amdgcn_mfma_f32_16x16x32_f16(a[kk], b, acc[jt], 0, 0, 0);
        }
    }

    const int bx = (boff >> 2) + w * 4 + hi;
    #pragma unroll
    for (int jt = 0; jt < 4; ++jt) {
        int n = n0 + jt * 16 + (l & 15);
        float bs = bias[n];
        f32x4 v = acc[jt];
        v[0] += bs; v[1] += bs; v[2] += bs; v[3] += bs;
        *(f32x4*)(C + ((size_t)(tt * 28 + bx) * N + n) * 4) = v;
    }
}

// ---------------------------------------------------------------------------
// xg GEMM from fp16 A (round-7 proven): layout [75][28][4H][4] f32.
// ---------------------------------------------------------------------------
template <int Ks>
__global__ __launch_bounds__(256) void gemm_xg(
    const _Float16* __restrict__ A, const _Float16* __restrict__ W,
    const float* __restrict__ bias, float* __restrict__ C, int Kv, int N) {
    constexpr int KP = Ks * 32;
    constexpr int LDK = KP + 8;
    __shared__ __align__(16) _Float16 Al[64][LDK];
    __shared__ __align__(16) _Float16 Wl[64][LDK];

    const int tid = threadIdx.x;
    const int tt = blockIdx.x >> 1;
    const int boff = (blockIdx.x & 1) * 48;
    const int n0 = blockIdx.y * 64;
    constexpr int HP = KP / 2;

    for (int idx = tid; idx < 64 * HP; idx += 256) {
        int row = idx / HP;
        int k = (idx - row * HP) * 2;
        unsigned int va = 0, vw = 0;
        if (k < Kv) {
            va = *(const unsigned int*)(A + (size_t)(tt * 112 + boff + row) * Kv + k);
            vw = *(const unsigned int*)(W + (size_t)(n0 + row) * Kv + k);
        }
        *(unsigned int*)&Al[row][k] = va;
        *(unsigned int*)&Wl[row][k] = vw;
    }
    __syncthreads();

    const int w = tid >> 6, l = tid & 63, hi = l >> 4;
    half8 a[Ks];
    #pragma unroll
    for (int kk = 0; kk < Ks; ++kk)
        a[kk] = *(const half8*)&Al[w * 16 + (l & 15)][kk * 32 + hi * 8];

    f32x4 acc[4];
    #pragma unroll
    for (int jt = 0; jt < 4; ++jt) {
        acc[jt] = f32x4{0.f, 0.f, 0.f, 0.f};
        #pragma unroll
        for (int kk = 0; kk < Ks; ++kk) {
            half8 b = *(const half8*)&Wl[jt * 16 + (l & 15)][kk * 32 + hi * 8];
            acc[jt] = __builtin_amdgcn_mfma_f32_16x16x32_f16(a[kk], b, acc[jt], 0, 0, 0);
        }
    }

    const int bx = (boff >> 2) + w * 4 + hi;
    #pragma unroll
    for (int jt = 0; jt < 4; ++jt) {
        int n = n0 + jt * 16 + (l & 15);
        float bs = bias[n];
        f32x4 v = acc[jt];
        v[0] += bs; v[1] += bs; v[2] += bs; v[3] += bs;
        *(f32x4*)(C + ((size_t)(tt * 28 + bx) * N + n) * 4) = v;
    }
}

#define FTAIL                                                                 \
    __builtin_amdgcn_sched_barrier(0);                                        \
    asm volatile("s_waitcnt lgkmcnt(0)");                                     \
    __builtin_amdgcn_sched_barrier(0);                                        \
    __builtin_amdgcn_s_barrier();                                             \
    __builtin_amdgcn_sched_barrier(0);

#define PICK(A4) ((hi & 2) ? ((hi & 1) ? A4[3] : A4[2]) : ((hi & 1) ? A4[1] : A4[0]))

#define ACT(aI, aF, aG4, aO)                                                  \
    float gI = PICK(aI), gF = PICK(aF), gG = PICK(aG4), gO = PICK(aO);        \
    float si = sigmf(gI), sf = sigmf(gF), tg = tanhx(gG), so = sigmf(gO);     \
    float cn = sf * cst + si * tg;                                            \
    cst = cn;                                                                 \
    float hn = so * tanhx(cn);                                                \
    _Float16 hv = (_Float16)hn;

// ---------------------------------------------------------------------------
// Single recurrent layer (round-7 proven, unchanged).
// ---------------------------------------------------------------------------
template <int H>
__global__ __launch_bounds__(4 * H) void lstm_rec(
    const float* __restrict__ xg, const _Float16* __restrict__ whh,
    _Float16* __restrict__ hout) {
    constexpr int Ks = H / 32;
    constexpr int LDH = H + 8;
    constexpr int XSTR = 448 * H;
    constexpr int HSTR = 112 * H;

    __shared__ __align__(16) _Float16 hbuf[2][4][LDH];

    const int tid = threadIdx.x;
    const int w = tid >> 6, l = tid & 63, hi = l >> 4;
    const int col = w * 16 + (l & 15);
    const int blk = blockIdx.x;

    half8 bw[4][Ks];
    #pragma unroll
    for (int G = 0; G < 4; ++G)
        #pragma unroll
        for (int kk = 0; kk < Ks; ++kk)
            bw[G][kk] = *(const half8*)(whh + (size_t)(G * H + col) * H + kk * 32 + hi * 8);

    for (int i = tid; i < 2 * 4 * LDH; i += 4 * H) ((_Float16*)hbuf)[i] = (_Float16)0;
    __syncthreads();

    const float* xp = xg + (size_t)blk * (4 * H * 4) + col * 16;
    _Float16* hop = hout + (size_t)(blk * 4 + hi) * H + col;

    f32x4 P0[4], P1[4], P2[4];
#define XLOAD(PA)                                                             \
    PA[0] = *(const f32x4*)(xp + 0);                                          \
    PA[1] = *(const f32x4*)(xp + 4);                                          \
    PA[2] = *(const f32x4*)(xp + 8);                                          \
    PA[3] = *(const f32x4*)(xp + 12);                                         \
    xp += XSTR;

    XLOAD(P0)
    XLOAD(P1)
    XLOAD(P2)

    float cst = 0.f;

#define LSTM_STEP(PA, CUR)                                                    \
    {                                                                         \
        half8 afr[Ks];                                                        \
        _Pragma("unroll") for (int kk = 0; kk < Ks; ++kk)                     \
            afr[kk] = *(const half8*)&hbuf[CUR][(l & 15) & 3][kk * 32 + hi * 8]; \
        f32x4 aI = PA[0], aF = PA[1], aG4 = PA[2], aO = PA[3];                \
        XLOAD(PA)                                                             \
        _Pragma("unroll") for (int kk = 0; kk < Ks; ++kk) {                   \
            aI = __builtin_amdgcn_mfma_f32_16x16x32_f16(afr[kk], bw[0][kk], aI, 0, 0, 0);  \
            aF = __builtin_amdgcn_mfma_f32_16x16x32_f16(afr[kk], bw[1][kk], aF, 0, 0, 0);  \
            aG4 = __builtin_amdgcn_mfma_f32_16x16x32_f16(afr[kk], bw[2][kk], aG4, 0, 0, 0);\
            aO = __builtin_amdgcn_mfma_f32_16x16x32_f16(afr[kk], bw[3][kk], aO, 0, 0, 0);  \
        }                                                                     \
        ACT(aI, aF, aG4, aO)                                                  \
        hbuf[CUR ^ 1][hi][col] = hv;                                          \
        *hop = hv;                                                            \
        hop += HSTR;                                                          \
        FTAIL                                                                 \
    }

    #pragma unroll 1
    for (int it = 0; it < 12; ++it) {
        LSTM_STEP(P0, 0) LSTM_STEP(P1, 1) LSTM_STEP(P2, 0)
        LSTM_STEP(P0, 1) LSTM_STEP(P1, 0) LSTM_STEP(P2, 1)
    }
    LSTM_STEP(P0, 0) LSTM_STEP(P1, 1) LSTM_STEP(P2, 0)
#undef LSTM_STEP
#undef XLOAD
}

// ---------------------------------------------------------------------------
// Quad-fused layers 2,3,4,5 + fused final linear. 25 blocks x 832 threads
// (13 waves): w0-3 = L2 (xg C-init), w4-7 = L3 (lag 1), w8-9 = L4 (lag 2),
// w10-11 = L5 (lag 3, publishes h5 into hb5 only), w12 = LIN (lag 4):
// online-accumulates out[b][o] += lw[o][t*32+hc] * h5_t[b][hc] via 4 MFMA
// per step, lw fragments 2-step prefetched (static LA/LB slots). 78 steps,
// one barrier each, all 13 waves execute exactly 78 FTAILs; LIN handles
// t=74 post-loop (hb5[0] is stable after the last barrier).
// ---------------------------------------------------------------------------
__global__ __launch_bounds__(832) void lstm_quad(
    const float* __restrict__ xg,        // [78][28][256][4] f32 (layer 2)
    const _Float16* __restrict__ whh2, const _Float16* __restrict__ whh3,
    const _Float16* __restrict__ wih3, const _Float16* __restrict__ whh4,
    const _Float16* __restrict__ wih4, const _Float16* __restrict__ whh5,
    const _Float16* __restrict__ wih5, const float* __restrict__ biasP,
    const _Float16* __restrict__ lwI,    // [75][4][16][32] fp16
    const float* __restrict__ lb,        // [60] f32
    float* __restrict__ outF) {          // [100][60] f32
    __shared__ __align__(16) _Float16 hb2[2][4][72], hp2[2][4][72];
    __shared__ __align__(16) _Float16 hb3[2][4][72], hp3[2][4][72];
    __shared__ __align__(16) _Float16 hb4[2][4][40], hp4[2][4][40];
    __shared__ __align__(16) _Float16 hb5[2][4][40];

    const int tid = threadIdx.x;
    const int w = tid >> 6, l = tid & 63, hi = l >> 4;
    const int lr = (l & 15) & 3;
    const int blk = blockIdx.x;

    for (int i = tid; i < 2 * 4 * 72; i += 832) {
        ((_Float16*)hb2)[i] = (_Float16)0; ((_Float16*)hp2)[i] = (_Float16)0;
        ((_Float16*)hb3)[i] = (_Float16)0; ((_Float16*)hp3)[i] = (_Float16)0;
    }
    for (int i = tid; i < 2 * 4 * 40; i += 832) {
        ((_Float16*)hb4)[i] = (_Float16)0; ((_Float16*)hp4)[i] = (_Float16)0;
        ((_Float16*)hb5)[i] = (_Float16)0;
    }
    __syncthreads();

    float cst = 0.f;

    if (w < 4) {  // ----- L2: xg C-init role -----
        const int col = w * 16 + (l & 15);
        half8 bw[4][2];
        #pragma unroll
        for (int G = 0; G < 4; ++G)
            #pragma unroll
            for (int kk = 0; kk < 2; ++kk)
                bw[G][kk] = *(const half8*)(whh2 + (size_t)(G * 64 + col) * 64 + kk * 32 + hi * 8);
        const float* xp = xg + (size_t)blk * 1024 + col * 16;
        f32x4 P0[4], P1[4], P2[4];
#define XLOADQ(PA)                                                            \
        PA[0] = *(const f32x4*)(xp + 0);                                      \
        PA[1] = *(const f32x4*)(xp + 4);                                      \
        PA[2] = *(const f32x4*)(xp + 8);                                      \
        PA[3] = *(const f32x4*)(xp + 12);                                     \
        xp += 28672;
        XLOADQ(P0)
        XLOADQ(P1)
        XLOADQ(P2)

#define QA(PA, CUR, S)                                                        \
        {                                                                     \
            if ((S) < 75) {                                                   \
                half8 afr[2];                                                 \
                _Pragma("unroll") for (int kk = 0; kk < 2; ++kk)              \
                    afr[kk] = *(const half8*)&hb2[CUR][lr][kk * 32 + hi * 8]; \
                f32x4 aI = PA[0], aF = PA[1], aG4 = PA[2], aO = PA[3];        \
                XLOADQ(PA)                                                    \
                _Pragma("unroll") for (int kk = 0; kk < 2; ++kk) {            \
                    aI = __builtin_amdgcn_mfma_f32_16x16x32_f16(afr[kk], bw[0][kk], aI, 0, 0, 0);  \
                    aF = __builtin_amdgcn_mfma_f32_16x16x32_f16(afr[kk], bw[1][kk], aF, 0, 0, 0);  \
                    aG4 = __builtin_amdgcn_mfma_f32_16x16x32_f16(afr[kk], bw[2][kk], aG4, 0, 0, 0);\
                    aO = __builtin_amdgcn_mfma_f32_16x16x32_f16(afr[kk], bw[3][kk], aO, 0, 0, 0);  \
                }                                                             \
                ACT(aI, aF, aG4, aO)                                          \
                hb2[(CUR) ^ 1][hi][col] = hv;                                 \
                hp2[(CUR) ^ 1][hi][col] = hv;                                 \
            }                                                                 \
            FTAIL                                                             \
        }
        #pragma unroll 1
        for (int it = 0; it < 13; ++it) {
            const int b6 = it * 6;
            QA(P0, 0, b6 + 0) QA(P1, 1, b6 + 1) QA(P2, 0, b6 + 2)
            QA(P0, 1, b6 + 3) QA(P1, 0, b6 + 4) QA(P2, 1, b6 + 5)
        }
#undef QA
#undef XLOADQ
    } else if (w < 8) {  // ----- L3: H=64, HIN=64, lag 1 -----
        const int col = (w - 4) * 16 + (l & 15);
        half8 bwB[4][2], bwI[4][2];
        #pragma unroll
        for (int G = 0; G < 4; ++G)
            #pragma unroll
            for (int kk = 0; kk < 2; ++kk) {
                bwB[G][kk] = *(const half8*)(whh3 + (size_t)(G * 64 + col) * 64 + kk * 32 + hi * 8);
                bwI[G][kk] = *(const half8*)(wih3 + (size_t)(G * 64 + col) * 64 + kk * 32 + hi * 8);
            }
        const float bI = biasP[col], bF = biasP[64 + col];
        const float bG = biasP[128 + col], bO = biasP[192 + col];
        #pragma unroll 1
        for (int s = 0; s < 78; ++s) {
            const int cur = s & 1;
            if (s >= 1 && s <= 75) {
                half8 afr[2], air[2];
                #pragma unroll
                for (int kk = 0; kk < 2; ++kk) {
                    afr[kk] = *(const half8*)&hb3[cur][lr][kk * 32 + hi * 8];
                    air[kk] = *(const half8*)&hp2[cur][lr][kk * 32 + hi * 8];
                }
                f32x4 aI = {bI, bI, bI, bI}, aF = {bF, bF, bF, bF};
                f32x4 aG4 = {bG, bG, bG, bG}, aO = {bO, bO, bO, bO};
                #pragma unroll
                for (int kk = 0; kk < 2; ++kk) {
                    aI = __builtin_amdgcn_mfma_f32_16x16x32_f16(afr[kk], bwB[0][kk], aI, 0, 0, 0);
                    aF = __builtin_amdgcn_mfma_f32_16x16x32_f16(afr[kk], bwB[1][kk], aF, 0, 0, 0);
                    aG4 = __builtin_amdgcn_mfma_f32_16x16x32_f16(afr[kk], bwB[2][kk], aG4, 0, 0, 0);
                    aO = __builtin_amdgcn_mfma_f32_16x16x32_f16(afr[kk], bwB[3][kk], aO, 0, 0, 0);
                }
                #pragma unroll
                for (int kk = 0; kk < 2; ++kk) {
                    aI = __builtin_amdgcn_mfma_f32_16x16x32_f16(air[kk], bwI[0][kk], aI, 0, 0, 0);
                    aF = __builtin_amdgcn_mfma_f32_16x16x32_f16(air[kk], bwI[1][kk], aF, 0, 0, 0);
                    aG4 = __builtin_amdgcn_mfma_f32_16x16x32_f16(air[kk], bwI[2][kk], aG4, 0, 0, 0);
                    aO = __builtin_amdgcn_mfma_f32_16x16x32_f16(air[kk], bwI[3][kk], aO, 0, 0, 0);
                }
                ACT(aI, aF, aG4, aO)
                hb3[cur ^ 1][hi][col] = hv;
                hp3[cur ^ 1][hi][col] = hv;
            }
            FTAIL
        }
    } else if (w < 10) {  // ----- L4: H=32, HIN=64, lag 2 -----
        const int col = (w - 8) * 16 + (l & 15);
        half8 bwB[4], bwI[4][2];
        #pragma unroll
        for (int G = 0; G < 4; ++G) {
            bwB[G] = *(const half8*)(whh4 + (size_t)(G * 32 + col) * 32 + hi * 8);
            #pragma unroll
            for (int kk = 0; kk < 2; ++kk)
                bwI[G][kk] = *(const half8*)(wih4 + (size_t)(G * 32 + col) * 64 + kk * 32 + hi * 8);
        }
        const float* bp = biasP + 256;
        const float bI = bp[col], bF = bp[32 + col], bG = bp[64 + col], bO = bp[96 + col];
        #pragma unroll 1
        for (int s = 0; s < 78; ++s) {
            const int cur = s & 1;
            if (s >= 2 && s <= 76) {
                half8 afr = *(const half8*)&hb4[cur][lr][hi * 8];
                half8 air[2];
                #pragma unroll
                for (int kk = 0; kk < 2; ++kk)
                    air[kk] = *(const half8*)&hp3[cur][lr][kk * 32 + hi * 8];
                f32x4 aI = {bI, bI, bI, bI}, aF = {bF, bF, bF, bF};
                f32x4 aG4 = {bG, bG, bG, bG}, aO = {bO, bO, bO, bO};
                aI = __builtin_amdgcn_mfma_f32_16x16x32_f16(afr, bwB[0], aI, 0, 0, 0);
                aF = __builtin_amdgcn_mfma_f32_16x16x32_f16(afr, bwB[1], aF, 0, 0, 0);
                aG4 = __builtin_amdgcn_mfma_f32_16x16x32_f16(afr, bwB[2], aG4, 0, 0, 0);
                aO = __builtin_amdgcn_mfma_f32_16x16x32_f16(afr, bwB[3], aO, 0, 0, 0);
                #pragma unroll
                for (int kk = 0; kk < 2; ++kk) {
                    aI = __builtin_amdgcn_mfma_f32_16x16x32_f16(air[kk], bwI[0][kk], aI, 0, 0, 0);
                    aF = __builtin_amdgcn_mfma_f32_16x16x32_f16(air[kk], bwI[1][kk], aF, 0, 0, 0);
                    aG4 = __builtin_amdgcn_mfma_f32_16x16x32_f16(air[kk], bwI[2][kk], aG4, 0, 0, 0);
                    aO = __builtin_amdgcn_mfma_f32_16x16x32_f16(air[kk], bwI[3][kk], aO, 0, 0, 0);
                }
                ACT(aI, aF, aG4, aO)
                hb4[cur ^ 1][hi][col] = hv;
                hp4[cur ^ 1][hi][col] = hv;
            }
            FTAIL
        }
    } else if (w < 12) {  // ----- L5: H=32, HIN=32, lag 3; publishes hb5 -----
        const int col = (w - 10) * 16 + (l & 15);
        half8 bwB[4], bwI[4];
        #pragma unroll
        for (int G = 0; G < 4; ++G) {
            bwB[G] = *(const half8*)(whh5 + (size_t)(G * 32 + col) * 32 + hi * 8);
            bwI[G] = *(const half8*)(wih5 + (size_t)(G * 32 + col) * 32 + hi * 8);
        }
        const float* bp = biasP + 384;
        const float bI = bp[col], bF = bp[32 + col], bG = bp[64 + col], bO = bp[96 + col];
        #pragma unroll 1
        for (int s = 0; s < 78; ++s) {
            const int cur = s & 1;
            if (s >= 3) {
                half8 afr = *(const half8*)&hb5[cur][lr][hi * 8];
                half8 air = *(const half8*)&hp4[cur][lr][hi * 8];
                f32x4 aI = {bI, bI, bI, bI}, aF = {bF, bF, bF, bF};
                f32x4 aG4 = {bG, bG, bG, bG}, aO = {bO, bO, bO, bO};
                aI = __builtin_amdgcn_mfma_f32_16x16x32_f16(afr, bwB[0], aI, 0, 0, 0);
                aF = __builtin_amdgcn_mfma_f32_16x16x32_f16(afr, bwB[1], aF, 0, 0, 0);
                aG4 = __builtin_amdgcn_mfma_f32_16x16x32_f16(afr, bwB[2], aG4, 0, 0, 0);
                aO = __builtin_amdgcn_mfma_f32_16x16x32_f16(afr, bwB[3], aO, 0, 0, 0);
                aI = __builtin_amdgcn_mfma_f32_16x16x32_f16(air, bwI[0], aI, 0, 0, 0);
                aF = __builtin_amdgcn_mfma_f32_16x16x32_f16(air, bwI[1], aF, 0, 0, 0);
                aG4 = __builtin_amdgcn_mfma_f32_16x16x32_f16(air, bwI[2], aG4, 0, 0, 0);
                aO = __builtin_amdgcn_mfma_f32_16x16x32_f16(air, bwI[3], aO, 0, 0, 0);
                ACT(aI, aF, aG4, aO)
                hb5[cur ^ 1][hi][col] = hv;
            }
            FTAIL
        }
    } else {  // ----- LIN: lag 4; out[b][o] += lw[o][t*32+hc]*h5_t[b][hc] -----
        const int ln = l & 15;
        const _Float16* lwp = lwI + (size_t)ln * 32 + hi * 8;
        half8 LA[4], LB[4];
        #pragma unroll
        for (int tl = 0; tl < 4; ++tl) {
            LA[tl] = *(const half8*)(lwp + (size_t)(0 * 4 + tl) * 512);
            LB[tl] = *(const half8*)(lwp + (size_t)(1 * 4 + tl) * 512);
        }
        f32x4 acc[4];
        #pragma unroll
        for (int tl = 0; tl < 4; ++tl) acc[tl] = f32x4{0.f, 0.f, 0.f, 0.f};

        #pragma unroll 1
        for (int it = 0; it < 39; ++it) {
            {  // even step s0 = 2*it, t = s0 - 4, reads hb5[0], uses LA
                int t = 2 * it - 4;
                if (t >= 0) {
                    half8 hf = *(const half8*)&hb5[0][lr][hi * 8];
                    #pragma unroll
                    for (int tl = 0; tl < 4; ++tl)
                        acc[tl] = __builtin_amdgcn_mfma_f32_16x16x32_f16(LA[tl], hf, acc[tl], 0, 0, 0);
                }
                int tn = t + 2;
                if (tn < 0) tn = 0;
                if (tn > 74) tn = 74;
                #pragma unroll
                for (int tl = 0; tl < 4; ++tl)
                    LA[tl] = *(const half8*)(lwp + ((size_t)tn * 4 + tl) * 512);
                FTAIL
            }
            {  // odd step s1 = 2*it+1, t = s1 - 4, reads hb5[1], uses LB
                int t = 2 * it - 3;
                if (t >= 0) {
                    half8 hf = *(const half8*)&hb5[1][lr][hi * 8];
                    #pragma unroll
                    for (int tl = 0; tl < 4; ++tl)
                        acc[tl] = __builtin_amdgcn_mfma_f32_16x16x32_f16(LB[tl], hf, acc[tl], 0, 0, 0);
                }
                int tn = t + 2;
                if (tn < 0) tn = 0;
                if (tn > 74) tn = 74;
                #pragma unroll
                for (int tl = 0; tl < 4; ++tl)
                    LB[tl] = *(const half8*)(lwp + ((size_t)tn * 4 + tl) * 512);
                FTAIL
            }
        }
        // post-loop: t = 74 (written by L5 at s=77 into hb5[0]; final barrier done)
        {
            half8 hf = *(const half8*)&hb5[0][lr][hi * 8];
            #pragma unroll
            for (int tl = 0; tl < 4; ++tl)
                acc[tl] = __builtin_amdgcn_mfma_f32_16x16x32_f16(LA[tl], hf, acc[tl], 0, 0, 0);
        }
        if (ln < 4) {
            int b = blk * 4 + ln;
            #pragma unroll
            for (int tl = 0; tl < 4; ++tl)
                #pragma unroll
                for (int r = 0; r < 4; ++r) {
                    int o = tl * 16 + hi * 4 + r;
                    if (o < 60) outF[b * 60 + o] = acc[tl][r] + lb[o];
                }
        }
    }
}

// ---------------------------------------------------------------------------
extern "C" void kernel_launch(void* const* d_in, const int* in_sizes, int n_in,
                              void* d_out, int out_size, void* d_ws, size_t ws_size,
                              hipStream_t stream) {
    const float* x = (const float*)d_in[0];
    const float* wih[6];
    const float* whhp[6];
    const float* bih[6];
    const float* bhh[6];
    for (int i = 0; i < 6; ++i) {
        wih[i] = (const float*)d_in[1 + 4 * i];
        whhp[i] = (const float*)d_in[2 + 4 * i];
        bih[i] = (const float*)d_in[3 + 4 * i];
        bhh[i] = (const float*)d_in[4 + 4 * i];
    }
    const float* lw = (const float*)d_in[25];
    const float* lb = (const float*)d_in[26];
    float* out = (float*)d_out;

    char* ws = (char*)d_ws;
    size_t cur = 0;
    auto alloc = [&](size_t b) {
        size_t o = cur;
        cur += (b + 255) & ~(size_t)255;
        return o;
    };
    _Float16* wihI0 = (_Float16*)(ws + alloc(38912 * 2));
    _Float16* wihI1 = (_Float16*)(ws + alloc(65536 * 2));
    _Float16* wihI2 = (_Float16*)(ws + alloc(32768 * 2));
    _Float16* wihP3 = (_Float16*)(ws + alloc(16384 * 2));
    _Float16* wihP4 = (_Float16*)(ws + alloc(8192 * 2));
    _Float16* wihP5 = (_Float16*)(ws + alloc(4096 * 2));
    _Float16* whhP[6];
    const size_t whhBytes[6] = {131072, 131072, 32768, 32768, 8192, 8192};
    for (int i = 0; i < 6; ++i) whhP[i] = (_Float16*)(ws + alloc(whhBytes[i]));
    _Float16* lwI = (_Float16*)(ws + alloc(153600 * 2));
    float* biasI = (float*)(ws + alloc(1280 * 4));
    float* biasP = (float*)(ws + alloc(512 * 4));
    float* xg = (float*)(ws + alloc((size_t)78 * 28 * 512 * 4 * 4));
    _Float16* h0 = (_Float16*)(ws + alloc((size_t)75 * 112 * 128 * 2));
    _Float16* h1 = (_Float16*)(ws + alloc((size_t)75 * 112 * 128 * 2));

    PrepPtrs pp;
    for (int i = 0; i < 6; ++i) {
        pp.wih[i] = wih[i];
        pp.whh[i] = whhp[i];
        pp.bi[i] = bih[i];
        pp.bh[i] = bhh[i];
        pp.whhP[i] = whhP[i];
    }
    pp.lw = lw;
    pp.wihI0 = wihI0;
    pp.wihI1 = wihI1;
    pp.wihI2 = wihI2;
    pp.wihP3 = wihP3;
    pp.wihP4 = wihP4;
    pp.wihP5 = wihP5;
    pp.biasI = biasI;
    pp.biasP = biasP;
    pp.lwI = lwI;
    prep_kernel<<<1927, 256, 0, stream>>>(pp);

    // layer 0 xg GEMM straight from f32 x, then rec layer 0
    gemm_xg0<<<dim3(150, 8), 256, 0, stream>>>(x, wihI0, biasI + 0, xg);
    lstm_rec<128><<<25, 512, 0, stream>>>(xg, whhP[0], h0);
    // layer 1: I=128, H=128
    gemm_xg<4><<<dim3(150, 8), 256, 0, stream>>>(h0, wihI1, biasI + 512, xg, 128, 512);
    lstm_rec<128><<<25, 512, 0, stream>>>(xg, whhP[1], h1);
    // layer 2 xg GEMM (I=128, H=64), then quad-fused layers 2..5 + linear
    gemm_xg<4><<<dim3(150, 4), 256, 0, stream>>>(h1, wihI2, biasI + 1024, xg, 128, 256);
    lstm_quad<<<25, 832, 0, stream>>>(xg, whhP[2], whhP[3], wihP3, whhP[4],
                                      wihP4, whhP[5], wihP5, biasP, lwI, lb, out);
}